// Round 3
// baseline (510.273 us; speedup 1.0000x reference)
//
#include <hip/hip_runtime.h>
#include <hip/hip_bf16.h>
#include <stdint.h>

typedef __attribute__((ext_vector_type(4))) float f32x4;
typedef __attribute__((ext_vector_type(8))) short short8;
typedef __attribute__((ext_vector_type(8))) unsigned short u16x8;
typedef __attribute__((ext_vector_type(4))) unsigned short u16x4;

typedef __attribute__((address_space(1))) const unsigned int as1_u32;
typedef __attribute__((address_space(3))) unsigned int as3_u32;
#define GLD16(src, dst) __builtin_amdgcn_global_load_lds((as1_u32*)(src), (as3_u32*)(dst), 16, 0, 0)

__device__ __forceinline__ unsigned short f2bf(float f) {
  unsigned int u = __float_as_uint(f);
  u += 0x7fffu + ((u >> 16) & 1u);
  return (unsigned short)(u >> 16);
}
__device__ __forceinline__ float bf2f(unsigned short h) {
  return __uint_as_float(((unsigned int)h) << 16);
}

// ---------------- kernel 0: W (512x512 f32) -> WT (bf16, transposed) ----------------
__global__ __launch_bounds__(256) void k_twp(const float* __restrict__ W,
                                             unsigned short* __restrict__ WT) {
  __shared__ float tile[64][65];
  int tid = threadIdx.x;
  int c = tid & 63, r0 = tid >> 6;
  int kb = blockIdx.x * 64, nb = blockIdx.y * 64;
#pragma unroll
  for (int rr = 0; rr < 16; ++rr) {
    int r = rr * 4 + r0;
    tile[r][c] = W[(size_t)(kb + r) * 512 + nb + c];
  }
  __syncthreads();
#pragma unroll
  for (int rr = 0; rr < 16; ++rr) {
    int r = rr * 4 + r0;
    WT[(size_t)(nb + r) * 512 + kb + c] = f2bf(tile[c][r]);
  }
}

// ---------------- kernel 1: Wh^T GEMM + fused s1/s2/f1/f2 epilogue ----------------
__global__ __launch_bounds__(256, 2) void k_gemm(const float* __restrict__ xa,
                                                 const float* __restrict__ xv,
                                                 const unsigned short* __restrict__ WT,
                                                 unsigned short* __restrict__ WhT,
                                                 const float* __restrict__ a,
                                                 float* __restrict__ s1, float* __restrict__ s2,
                                                 float* __restrict__ f1, float* __restrict__ f2) {
  __shared__ __align__(16) unsigned short Al[64 * 64];    // 8KB
  __shared__ __align__(16) unsigned short Bl[512 * 64];   // 64KB
  __shared__ float a1l[512], a2l[512];                    // 4KB
  __shared__ float sp1[4][64], sp2[4][64];                // 2KB
  int tid = threadIdx.x;
  int rblk = blockIdx.x;
  int R0g = rblk * 64;
  int b = R0g >> 11;
  int iloc = R0g & 2047;
  const float* Abase = (iloc < 1024)
      ? (xa + ((size_t)b * 1024 + iloc) * 512)
      : (xv + ((size_t)b * 1024 + (iloc - 1024)) * 512);

  int lane = tid & 63;
  int wid = tid >> 6;
  int wc = wid;

#pragma unroll
  for (int i = 0; i < 2; ++i) {
    a1l[i * 256 + tid] = a[i * 256 + tid];
    a2l[i * 256 + tid] = a[512 + i * 256 + tid];
  }

  f32x4 acc[4][8];
#pragma unroll
  for (int i = 0; i < 4; ++i)
#pragma unroll
    for (int j = 0; j < 8; ++j) acc[i][j] = (f32x4){0.f, 0.f, 0.f, 0.f};

  for (int kt = 0; kt < 8; ++kt) {
    int k0 = kt * 64;
    __syncthreads();
#pragma unroll
    for (int pass = 0; pass < 4; ++pass) {
      int row = pass * 16 + (tid >> 4);
      int gg = tid & 15;
      float4 v = *((const float4*)(Abase + (size_t)row * 512 + k0) + gg);
      u16x4 pk;
      pk.x = f2bf(v.x); pk.y = f2bf(v.y); pk.z = f2bf(v.z); pk.w = f2bf(v.w);
      *(u16x4*)((char*)Al + row * 128 + ((gg * 8) ^ ((row & 7) << 4))) = pk;
    }
#pragma unroll
    for (int pass = 0; pass < 16; ++pass) {
      int n = pass * 32 + (tid >> 3);
      int g = tid & 7;
      const unsigned short* src = WT + (size_t)n * 512 + k0 + ((g ^ (n & 7)) << 3);
      unsigned short* dst = Bl + pass * 2048 + wid * 512;
      GLD16(src, dst);
    }
    __syncthreads();
#pragma unroll
    for (int kc = 0; kc < 2; ++kc) {
      int u = kc * 4 + (lane >> 4);
      short8 af[4];
#pragma unroll
      for (int mf = 0; mf < 4; ++mf) {
        int row = mf * 16 + (lane & 15);
        af[mf] = *(const short8*)((const char*)Al + row * 128 + (((u ^ (row & 7)) & 7) << 4));
      }
#pragma unroll
      for (int nf = 0; nf < 8; ++nf) {
        int n = wc * 128 + nf * 16 + (lane & 15);
        short8 bv = *(const short8*)((const char*)Bl + n * 128 + (((u ^ (n & 7)) & 7) << 4));
#pragma unroll
        for (int mf = 0; mf < 4; ++mf)
          acc[mf][nf] = __builtin_amdgcn_mfma_f32_16x16x32_bf16(af[mf], bv, acc[mf][nf], 0, 0, 0);
      }
    }
  }

  // ---- epilogue A: write WhT[b][n][j] ----
#pragma unroll
  for (int mf = 0; mf < 4; ++mf) {
    int jrow = iloc + mf * 16 + ((lane >> 4) << 2);
#pragma unroll
    for (int nf = 0; nf < 8; ++nf) {
      int n = wc * 128 + nf * 16 + (lane & 15);
      u16x4 pk;
#pragma unroll
      for (int e = 0; e < 4; ++e) pk[e] = f2bf(acc[mf][nf][e]);
      *(u16x4*)(WhT + ((size_t)b * 512 + n) * 2048 + jrow) = pk;
    }
  }

  // ---- epilogue B: s1/s2 from fp32 acc (j = mf*16 + u*4 + e, n = wc*128+nf*16+(lane&15)) ----
  float p1[4][4], p2[4][4];
#pragma unroll
  for (int mf = 0; mf < 4; ++mf)
#pragma unroll
    for (int e = 0; e < 4; ++e) { p1[mf][e] = 0.f; p2[mf][e] = 0.f; }
#pragma unroll
  for (int nf = 0; nf < 8; ++nf) {
    int n = wc * 128 + nf * 16 + (lane & 15);
    float w1 = a1l[n], w2 = a2l[n];
#pragma unroll
    for (int mf = 0; mf < 4; ++mf)
#pragma unroll
      for (int e = 0; e < 4; ++e) {
        p1[mf][e] += acc[mf][nf][e] * w1;
        p2[mf][e] += acc[mf][nf][e] * w2;
      }
  }
#pragma unroll
  for (int mask = 1; mask < 16; mask <<= 1) {
#pragma unroll
    for (int mf = 0; mf < 4; ++mf)
#pragma unroll
      for (int e = 0; e < 4; ++e) {
        p1[mf][e] += __shfl_xor(p1[mf][e], mask);
        p2[mf][e] += __shfl_xor(p2[mf][e], mask);
      }
  }
  if ((lane & 15) == 0) {
    int u = lane >> 4;
#pragma unroll
    for (int mf = 0; mf < 4; ++mf)
#pragma unroll
      for (int e = 0; e < 4; ++e) {
        int jl = mf * 16 + u * 4 + e;
        sp1[wc][jl] = p1[mf][e];
        sp2[wc][jl] = p2[mf][e];
      }
  }
  __syncthreads();
  if (tid < 64) {
    float v1 = sp1[0][tid] + sp1[1][tid] + sp1[2][tid] + sp1[3][tid];
    float v2 = sp2[0][tid] + sp2[1][tid] + sp2[2][tid] + sp2[3][tid];
    size_t o = (size_t)b * 2048 + iloc + tid;
    s1[o] = v1; s2[o] = v2;
    f1[o] = __expf(v2);
    f2[o] = __expf(0.1f * v2);
  }
}

// ---------------- kernel 2: fused attention, counted-vmcnt double-buffered pipeline ----------------
// LDS: Bl 64KB + AdjL 32KB + Pl 16KB + tables 16KB = 128.6KB -> 1 WG/CU, 8 waves.
__global__ __launch_bounds__(512, 2) void k_attn(const int* __restrict__ adj,
                                                 const unsigned short* __restrict__ WhT,
                                                 const float* __restrict__ s1g,
                                                 const float* __restrict__ s2g,
                                                 const float* __restrict__ f1g,
                                                 const float* __restrict__ f2g,
                                                 float* __restrict__ out) {
  __shared__ __align__(16) unsigned short Bl[2][512 * 32];   // row 64B, swz g^(n&3)
  __shared__ __align__(16) int AdjL[2][128 * 32];            // row 128B, swz g^(r&7)
  __shared__ __align__(16) unsigned short Pl[2][128 * 32];   // row 64B, swz g^(r&3)
  __shared__ float f1l[2048], f2l[2048];
  __shared__ float zl[128];
  __shared__ float red[8];
  int tid = threadIdx.x;
  int bx = blockIdx.x;
  int q = bx >> 3, xcd = bx & 7;
  int b = xcd * 2 + (q & 1);       // XCD k owns batches {2k,2k+1}: their WhT L2-resident
  int rb = q >> 1;
  int R0 = rb * 128;

  int lane = tid & 63, wid = tid >> 6;
  int wr2 = wid >> 2, wc = wid & 3;
  int r = tid >> 2, qc = tid & 3;

  const unsigned short* whbase = WhT + (size_t)b * 512 * 2048;
  const int* adjbase = adj + ((size_t)b * 2048 + R0) * 2048;

  auto issue = [&](int ph) {
    int j0 = ph << 5;
    int buf = ph & 1;
#pragma unroll
    for (int p = 0; p < 4; ++p) {
      int G = p * 512 + tid;
      int n = G >> 2, g = G & 3;
      const unsigned short* src = whbase + (size_t)n * 2048 + j0 + ((g ^ (n & 3)) << 3);
      GLD16(src, (unsigned short*)Bl[buf] + G * 8);
    }
#pragma unroll
    for (int p = 0; p < 2; ++p) {
      int G = p * 512 + tid;
      int rr = G >> 3, g = G & 7;
      const int* src = adjbase + (size_t)rr * 2048 + j0 + ((g ^ (rr & 7)) << 2);
      GLD16(src, AdjL[buf] + G * 4);
    }
  };

  issue(0);

  // ---- tables + gmax ----
  float lm = -1e30f;
#pragma unroll
  for (int i = 0; i < 4; ++i) {
    int idx = i * 512 + tid;
    float v = s2g[(size_t)b * 2048 + idx];
    f1l[idx] = f1g[(size_t)b * 2048 + idx];
    f2l[idx] = f2g[(size_t)b * 2048 + idx];
    lm = fmaxf(lm, v);
  }
#pragma unroll
  for (int s = 1; s < 64; s <<= 1) lm = fmaxf(lm, __shfl_xor(lm, s));
  if (lane == 0) red[wid] = lm;
  __syncthreads();
  float gmax = red[0];
#pragma unroll
  for (int i = 1; i < 8; ++i) gmax = fmaxf(gmax, red[i]);

  float s1r = s1g[(size_t)b * 2048 + R0 + r];
  float t0v = s1r + gmax;
  float M = (t0v > 0.f) ? t0v : 0.1f * t0v;
  float E1 = __expf(s1r - M);
  float E2 = __expf(0.1f * s1r - M);
  float T1 = __expf(-s1r);
  float zacc = 0.f;

  f32x4 acc[4][8];
#pragma unroll
  for (int i = 0; i < 4; ++i)
#pragma unroll
    for (int j = 0; j < 8; ++j) acc[i][j] = (f32x4){0.f, 0.f, 0.f, 0.f};

  auto computeP = [&](int ph) {
    int buf = ph & 1;
    int jb = (ph << 5) + qc * 8;
    int4 a0 = *(const int4*)(AdjL[buf] + r * 32 + (((qc * 2 + 0) ^ (r & 7)) << 2));
    int4 a1 = *(const int4*)(AdjL[buf] + r * 32 + (((qc * 2 + 1) ^ (r & 7)) << 2));
    float4 A1 = *(const float4*)(f1l + jb);
    float4 B1 = *(const float4*)(f1l + jb + 4);
    float4 A2 = *(const float4*)(f2l + jb);
    float4 B2 = *(const float4*)(f2l + jb + 4);
    int av[8] = {a0.x, a0.y, a0.z, a0.w, a1.x, a1.y, a1.z, a1.w};
    float f1v[8] = {A1.x, A1.y, A1.z, A1.w, B1.x, B1.y, B1.z, B1.w};
    float f2v[8] = {A2.x, A2.y, A2.z, A2.w, B2.x, B2.y, B2.z, B2.w};
    u16x8 pk;
#pragma unroll
    for (int c = 0; c < 8; ++c) {
      bool pos = f1v[c] > T1;
      float Ev = pos ? E1 : E2;
      float Fv = pos ? f1v[c] : f2v[c];
      float p = (av[c] > 0) ? Ev * Fv : 0.f;
      unsigned short pb = f2bf(p);
      zacc += bf2f(pb);
      pk[c] = pb;
    }
    *(u16x8*)((char*)Pl[buf] + r * 64 + ((qc ^ (r & 3)) << 4)) = pk;
  };

  auto mfmaPhase = [&](int ph) {
    int buf = ph & 1;
    int u = lane >> 4;
    short8 af[4];
#pragma unroll
    for (int mf = 0; mf < 4; ++mf) {
      int row = wr2 * 64 + mf * 16 + (lane & 15);
      af[mf] = *(const short8*)((const char*)Pl[buf] + row * 64 + ((u ^ (row & 3)) << 4));
    }
#pragma unroll
    for (int nf = 0; nf < 8; ++nf) {
      int n = wc * 128 + nf * 16 + (lane & 15);
      short8 bv = *(const short8*)((const char*)Bl[buf] + n * 64 + ((u ^ (n & 3)) << 4));
#pragma unroll
      for (int mf = 0; mf < 4; ++mf)
        acc[mf][nf] = __builtin_amdgcn_mfma_f32_16x16x32_bf16(af[mf], bv, acc[mf][nf], 0, 0, 0);
    }
  };

  // ---- prologue: phase 0 (issue(0) already drained by the gmax __syncthreads) ----
  issue(1);
  computeP(0);
  asm volatile("s_waitcnt lgkmcnt(0)" ::: "memory");
  __builtin_amdgcn_s_barrier();
  mfmaPhase(0);

  for (int ph = 1; ph < 64; ++ph) {
    __builtin_amdgcn_s_barrier();                       // A: all waves done mfma(ph-1)
    if (ph < 63) {
      issue(ph + 1);                                    // into buffer mfma(ph-1) just released
      asm volatile("s_waitcnt vmcnt(6)" ::: "memory");  // retire issue(ph) -> cur bufs ready
    } else {
      asm volatile("s_waitcnt vmcnt(0)" ::: "memory");
    }
    computeP(ph);
    asm volatile("s_waitcnt lgkmcnt(0)" ::: "memory");
    __builtin_amdgcn_s_barrier();                       // B: Pl/Bl(cur) visible to all
    mfmaPhase(ph);
  }

  // ---- z reduction (4 qc threads per row are adjacent lanes) ----
  zacc += __shfl_xor(zacc, 1);
  zacc += __shfl_xor(zacc, 2);
  if (qc == 0) zl[r] = zacc;
  __syncthreads();

  // ---- epilogue: h' = elu(acc / z) ----
  float* obase;
  if (R0 < 1024) obase = out + ((size_t)b * 1024 + R0) * 512;
  else obase = out + (size_t)8388608 + ((size_t)b * 1024 + (R0 - 1024)) * 512;
#pragma unroll
  for (int mf = 0; mf < 4; ++mf) {
    int row0 = wr2 * 64 + mf * 16 + ((lane >> 4) << 2);
    float zi[4];
#pragma unroll
    for (int e = 0; e < 4; ++e) zi[e] = 1.f / zl[row0 + e];
#pragma unroll
    for (int nf = 0; nf < 8; ++nf) {
      int n = wc * 128 + nf * 16 + (lane & 15);
#pragma unroll
      for (int e = 0; e < 4; ++e) {
        float v = acc[mf][nf][e] * zi[e];
        v = (v > 0.f) ? v : (__expf(v) - 1.f);
        obase[(size_t)(row0 + e) * 512 + n] = v;
      }
    }
  }
}

extern "C" void kernel_launch(void* const* d_in, const int* in_sizes, int n_in,
                              void* d_out, int out_size, void* d_ws, size_t ws_size,
                              hipStream_t stream) {
  (void)in_sizes; (void)n_in; (void)out_size; (void)ws_size;
  const float* x_a = (const float*)d_in[0];
  const float* x_v = (const float*)d_in[1];
  const int*   adj = (const int*)d_in[2];
  const float* W   = (const float*)d_in[3];
  const float* a   = (const float*)d_in[4];
  float* out = (float*)d_out;

  char* ws = (char*)d_ws;
  unsigned short* WT  = (unsigned short*)ws;                       // 512 KB
  unsigned short* WhT = (unsigned short*)(ws + (1u << 19));        // 32 MB
  float* s1 = (float*)(ws + (1u << 19) + (1u << 25));              // 128 KB each
  float* s2 = s1 + 32768;
  float* f1 = s2 + 32768;
  float* f2 = f1 + 32768;

  hipLaunchKernelGGL(k_twp,  dim3(8, 8), dim3(256), 0, stream, W, WT);
  hipLaunchKernelGGL(k_gemm, dim3(512),  dim3(256), 0, stream, x_a, x_v, WT, WhT, a, s1, s2, f1, f2);
  hipLaunchKernelGGL(k_attn, dim3(256),  dim3(512), 0, stream, adj, WhT, s1, s2, f1, f2, out);
}